// Round 4
// baseline (382.066 us; speedup 1.0000x reference)
//
#include <hip/hip_runtime.h>
#include <hip/hip_bf16.h>

// FraudSNN fused kernel: GEMM (bf16 MFMA) + LIF recurrence, T=10, F=256, H=512.
// R4: kill register spills (R3 had VGPR capped at 128 by launch_bounds(512,2) ->
// ~350 MB scratch traffic: WRITE_SIZE 94 MB, FETCH +260 MB). Now launch_bounds(512,1)
// (256-VGPR budget, ~200 live regs, no spill) + W1 preconverted to bf16 in d_ws.

typedef short short8 __attribute__((ext_vector_type(8)));
typedef float f32x4 __attribute__((ext_vector_type(4)));

__device__ __forceinline__ unsigned short bfbits(float f) {
  union { __hip_bfloat16 h; unsigned short u; } c;
  c.h = __float2bfloat16(f);   // hardware RNE
  return c.u;
}

__device__ __forceinline__ unsigned int bfpack(float a, float b) {
  return (unsigned int)bfbits(a) | ((unsigned int)bfbits(b) << 16);
}

__device__ __forceinline__ float fast_sigmoid(float z) {
  float e = __expf(-z);
  return __builtin_amdgcn_rcpf(1.0f + e);
}

__global__ void w1_to_bf16(const float* __restrict__ w1, unsigned short* __restrict__ o) {
  int i = blockIdx.x * 256 + threadIdx.x;      // 32768 float4s = 131072 floats
  float4 v = reinterpret_cast<const float4*>(w1)[i];
  reinterpret_cast<uint2*>(o)[i] = make_uint2(bfpack(v.x, v.y), bfpack(v.z, v.w));
}

// 512 threads = 8 waves. Block handles 64 batch rows. Wave w owns all 64 rows x h in [w*64, w*64+64).
template <bool USE_WS>
__global__ __launch_bounds__(512, 1)
void snn_main(const float* __restrict__ x,
              const unsigned short* __restrict__ w1bf,  // bf16 W1 (if USE_WS)
              const float* __restrict__ w1f,            // fp32 W1 (fallback)
              const float* __restrict__ b1,
              const float* __restrict__ w2,
              const float* __restrict__ b2,
              float* __restrict__ out)
{
  __shared__ __align__(16) unsigned short xt[64][264];  // bf16 bits, +8 pad
  __shared__ float red[64][9];                          // [row][wave] partial cur2

  const int tid  = threadIdx.x;
  const int lane = tid & 63;
  const int wave = tid >> 6;
  const int l15  = lane & 15;
  const int lq   = lane >> 4;
  const long b0  = (long)blockIdx.x * 64;
  const int h0   = wave * 64;

  float w2l[4], b1l[4];
#pragma unroll
  for (int ct = 0; ct < 4; ++ct) {
    int h = h0 + ct * 16 + l15;
    w2l[ct] = w2[h];
    b1l[ct] = b1[h];
  }
  const float bias2 = b2[0];

  float mem1[4][4][4];
#pragma unroll
  for (int rt = 0; rt < 4; ++rt)
#pragma unroll
    for (int ct = 0; ct < 4; ++ct)
#pragma unroll
      for (int e = 0; e < 4; ++e) mem1[rt][ct][e] = 0.f;

  float mem2 = 0.f, spksum = 0.f;   // meaningful on tid<64 only

  for (int t = 0; t < 10; ++t) {
    // ---- stage x[b0..b0+63, t, :] -> LDS bf16 ----
#pragma unroll
    for (int j = 0; j < 8; ++j) {
      int i  = tid + j * 512;
      int r  = i >> 6;
      int c4 = i & 63;
      const float4 v = *reinterpret_cast<const float4*>(x + ((b0 + r) * 10 + t) * 256 + c4 * 4);
      *reinterpret_cast<uint2*>(&xt[r][c4 * 4]) =
          make_uint2(bfpack(v.x, v.y), bfpack(v.z, v.w));
    }
    __syncthreads();

    // ---- GEMM: cur1 = x @ W1^T + b1 (acc init = b1) ----
    f32x4 acc[4][4];
#pragma unroll
    for (int rt = 0; rt < 4; ++rt)
#pragma unroll
      for (int ct = 0; ct < 4; ++ct) {
        f32x4 c = { b1l[ct], b1l[ct], b1l[ct], b1l[ct] };
        acc[rt][ct] = c;
      }

#pragma unroll
    for (int kk = 0; kk < 8; ++kk) {
      short8 a[4], bfr[4];
#pragma unroll
      for (int rt = 0; rt < 4; ++rt)
        a[rt] = *reinterpret_cast<const short8*>(&xt[rt * 16 + l15][kk * 32 + lq * 8]);
#pragma unroll
      for (int ct = 0; ct < 4; ++ct) {
        if constexpr (USE_WS) {
          bfr[ct] = *reinterpret_cast<const short8*>(
              w1bf + (h0 + ct * 16 + l15) * 256 + kk * 32 + lq * 8);
        } else {
          const float* wp = w1f + (h0 + ct * 16 + l15) * 256 + kk * 32 + lq * 8;
          const float4 v0 = *reinterpret_cast<const float4*>(wp);
          const float4 v1 = *reinterpret_cast<const float4*>(wp + 4);
          union { unsigned int u[4]; short8 s; } cv;
          cv.u[0] = bfpack(v0.x, v0.y);
          cv.u[1] = bfpack(v0.z, v0.w);
          cv.u[2] = bfpack(v1.x, v1.y);
          cv.u[3] = bfpack(v1.z, v1.w);
          bfr[ct] = cv.s;
        }
      }
#pragma unroll
      for (int rt = 0; rt < 4; ++rt)
#pragma unroll
        for (int ct = 0; ct < 4; ++ct)
          acc[rt][ct] = __builtin_amdgcn_mfma_f32_16x16x32_bf16(a[rt], bfr[ct], acc[rt][ct], 0, 0, 0);
    }

    // ---- LIF1 + partial W2 dot ----
    float pr[4][4];
#pragma unroll
    for (int rt = 0; rt < 4; ++rt)
#pragma unroll
      for (int e = 0; e < 4; ++e) pr[rt][e] = 0.f;

#pragma unroll
    for (int rt = 0; rt < 4; ++rt)
#pragma unroll
      for (int ct = 0; ct < 4; ++ct)
#pragma unroll
        for (int e = 0; e < 4; ++e) {
          float m   = fmaf(mem1[rt][ct][e], 0.9f, acc[rt][ct][e]);  // beta*mem + cur1
          float spk = fast_sigmoid(fmaf(m, 10.f, -10.f));           // sigmoid(10*(m-1))
          mem1[rt][ct][e] = m - spk;
          pr[rt][e] = fmaf(spk, w2l[ct], pr[rt][e]);
        }

    // reduce across the 16 lanes (h axis) sharing each row
#pragma unroll
    for (int rt = 0; rt < 4; ++rt)
#pragma unroll
      for (int e = 0; e < 4; ++e) {
        float v = pr[rt][e];
        v += __shfl_xor(v, 1);
        v += __shfl_xor(v, 2);
        v += __shfl_xor(v, 4);
        v += __shfl_xor(v, 8);
        pr[rt][e] = v;
      }
    if (l15 == 0) {
#pragma unroll
      for (int rt = 0; rt < 4; ++rt)
#pragma unroll
        for (int e = 0; e < 4; ++e)
          red[rt * 16 + lq * 4 + e][wave] = pr[rt][e];
    }
    __syncthreads();

    // ---- LIF2 on wave 0: one thread per batch row ----
    if (tid < 64) {
      float c2 = bias2;
#pragma unroll
      for (int w = 0; w < 8; ++w) c2 += red[tid][w];
      float m   = fmaf(mem2, 0.9f, c2);
      float spk = fast_sigmoid(fmaf(m, 10.f, -10.f));
      mem2   = m - spk;
      spksum += spk;
    }
    __syncthreads();
  }

  if (tid < 64) {
    float y = fast_sigmoid(spksum * 0.1f);
    out[b0 + tid] = y;                      // FLOAT32 output
  }
}

extern "C" void kernel_launch(void* const* d_in, const int* in_sizes, int n_in,
                              void* d_out, int out_size, void* d_ws, size_t ws_size,
                              hipStream_t stream) {
  const float* x  = (const float*)d_in[0];
  const float* W1 = (const float*)d_in[1];
  const float* b1 = (const float*)d_in[2];
  const float* W2 = (const float*)d_in[3];
  const float* b2 = (const float*)d_in[4];
  float* out = (float*)d_out;
  (void)in_sizes; (void)n_in;

  const int grid = out_size / 64;   // out_size == B == 32768 -> 512 blocks

  if (ws_size >= 512 * 256 * sizeof(unsigned short)) {
    unsigned short* w1bf = (unsigned short*)d_ws;   // 256 KB
    w1_to_bf16<<<128, 256, 0, stream>>>(W1, w1bf);
    snn_main<true><<<grid, 512, 0, stream>>>(x, w1bf, W1, b1, W2, b2, out);
  } else {
    snn_main<false><<<grid, 512, 0, stream>>>(x, nullptr, W1, b1, W2, b2, out);
  }
}

// Round 5
// 343.467 us; speedup vs baseline: 1.1124x; 1.1124x over previous
//
#include <hip/hip_runtime.h>
#include <hip/hip_bf16.h>

// FraudSNN fused kernel: GEMM (bf16 MFMA) + LIF recurrence, T=10, F=256, H=512.
// R5: compiler was pinning VGPR=128 (its own 4-waves/EU occupancy heuristic) and
// spilling ~70 regs -> ~350 MB scratch HBM traffic (WRITE 119 MB, FETCH +380 MB).
// Force the tradeoff with amdgpu_waves_per_eu(2,2): exactly 8 waves/CU (our one
// block), 256-VGPR budget, no spills. t-loop pinned to unroll 1 to bound pressure.

typedef short short8 __attribute__((ext_vector_type(8)));
typedef float f32x4 __attribute__((ext_vector_type(4)));

__device__ __forceinline__ unsigned short bfbits(float f) {
  union { __hip_bfloat16 h; unsigned short u; } c;
  c.h = __float2bfloat16(f);   // hardware RNE
  return c.u;
}

__device__ __forceinline__ unsigned int bfpack(float a, float b) {
  return (unsigned int)bfbits(a) | ((unsigned int)bfbits(b) << 16);
}

__device__ __forceinline__ float fast_sigmoid(float z) {
  float e = __expf(-z);
  return __builtin_amdgcn_rcpf(1.0f + e);
}

__global__ void w1_to_bf16(const float* __restrict__ w1, unsigned short* __restrict__ o) {
  int i = blockIdx.x * 256 + threadIdx.x;      // 32768 float4s = 131072 floats
  float4 v = reinterpret_cast<const float4*>(w1)[i];
  reinterpret_cast<uint2*>(o)[i] = make_uint2(bfpack(v.x, v.y), bfpack(v.z, v.w));
}

// 512 threads = 8 waves. Block handles 64 batch rows. Wave w owns all 64 rows x h in [w*64, w*64+64).
template <bool USE_WS>
__global__
__attribute__((amdgpu_flat_work_group_size(512, 512), amdgpu_waves_per_eu(2, 2)))
void snn_main(const float* __restrict__ x,
              const unsigned short* __restrict__ w1bf,  // bf16 W1 (if USE_WS)
              const float* __restrict__ w1f,            // fp32 W1 (fallback)
              const float* __restrict__ b1,
              const float* __restrict__ w2,
              const float* __restrict__ b2,
              float* __restrict__ out)
{
  __shared__ __align__(16) unsigned short xt[64][264];  // bf16 bits, +8 pad
  __shared__ float red[64][9];                          // [row][wave] partial cur2

  const int tid  = threadIdx.x;
  const int lane = tid & 63;
  const int wave = tid >> 6;
  const int l15  = lane & 15;
  const int lq   = lane >> 4;
  const long b0  = (long)blockIdx.x * 64;
  const int h0   = wave * 64;

  float w2l[4], b1l[4];
#pragma unroll
  for (int ct = 0; ct < 4; ++ct) {
    int h = h0 + ct * 16 + l15;
    w2l[ct] = w2[h];
    b1l[ct] = b1[h];
  }
  const float bias2 = b2[0];

  float mem1[4][4][4];
#pragma unroll
  for (int rt = 0; rt < 4; ++rt)
#pragma unroll
    for (int ct = 0; ct < 4; ++ct)
#pragma unroll
      for (int e = 0; e < 4; ++e) mem1[rt][ct][e] = 0.f;

  float mem2 = 0.f, spksum = 0.f;   // meaningful on tid<64 only

#pragma unroll 1
  for (int t = 0; t < 10; ++t) {
    // ---- stage x[b0..b0+63, t, :] -> LDS bf16 ----
#pragma unroll
    for (int j = 0; j < 8; ++j) {
      int i  = tid + j * 512;
      int r  = i >> 6;
      int c4 = i & 63;
      const float4 v = *reinterpret_cast<const float4*>(x + ((b0 + r) * 10 + t) * 256 + c4 * 4);
      *reinterpret_cast<uint2*>(&xt[r][c4 * 4]) =
          make_uint2(bfpack(v.x, v.y), bfpack(v.z, v.w));
    }
    __syncthreads();

    // ---- GEMM: cur1 = x @ W1^T + b1 (acc init = b1) ----
    f32x4 acc[4][4];
#pragma unroll
    for (int rt = 0; rt < 4; ++rt)
#pragma unroll
      for (int ct = 0; ct < 4; ++ct) {
        f32x4 c = { b1l[ct], b1l[ct], b1l[ct], b1l[ct] };
        acc[rt][ct] = c;
      }

#pragma unroll
    for (int kk = 0; kk < 8; ++kk) {
      short8 a[4], bfr[4];
#pragma unroll
      for (int rt = 0; rt < 4; ++rt)
        a[rt] = *reinterpret_cast<const short8*>(&xt[rt * 16 + l15][kk * 32 + lq * 8]);
#pragma unroll
      for (int ct = 0; ct < 4; ++ct) {
        if constexpr (USE_WS) {
          bfr[ct] = *reinterpret_cast<const short8*>(
              w1bf + (h0 + ct * 16 + l15) * 256 + kk * 32 + lq * 8);
        } else {
          const float* wp = w1f + (h0 + ct * 16 + l15) * 256 + kk * 32 + lq * 8;
          const float4 v0 = *reinterpret_cast<const float4*>(wp);
          const float4 v1 = *reinterpret_cast<const float4*>(wp + 4);
          union { unsigned int u[4]; short8 s; } cv;
          cv.u[0] = bfpack(v0.x, v0.y);
          cv.u[1] = bfpack(v0.z, v0.w);
          cv.u[2] = bfpack(v1.x, v1.y);
          cv.u[3] = bfpack(v1.z, v1.w);
          bfr[ct] = cv.s;
        }
      }
#pragma unroll
      for (int rt = 0; rt < 4; ++rt)
#pragma unroll
        for (int ct = 0; ct < 4; ++ct)
          acc[rt][ct] = __builtin_amdgcn_mfma_f32_16x16x32_bf16(a[rt], bfr[ct], acc[rt][ct], 0, 0, 0);
    }

    // ---- LIF1 + partial W2 dot ----
    float pr[4][4];
#pragma unroll
    for (int rt = 0; rt < 4; ++rt)
#pragma unroll
      for (int e = 0; e < 4; ++e) pr[rt][e] = 0.f;

#pragma unroll
    for (int rt = 0; rt < 4; ++rt)
#pragma unroll
      for (int ct = 0; ct < 4; ++ct)
#pragma unroll
        for (int e = 0; e < 4; ++e) {
          float m   = fmaf(mem1[rt][ct][e], 0.9f, acc[rt][ct][e]);  // beta*mem + cur1
          float spk = fast_sigmoid(fmaf(m, 10.f, -10.f));           // sigmoid(10*(m-1))
          mem1[rt][ct][e] = m - spk;
          pr[rt][e] = fmaf(spk, w2l[ct], pr[rt][e]);
        }

    // reduce across the 16 lanes (h axis) sharing each row
#pragma unroll
    for (int rt = 0; rt < 4; ++rt)
#pragma unroll
      for (int e = 0; e < 4; ++e) {
        float v = pr[rt][e];
        v += __shfl_xor(v, 1);
        v += __shfl_xor(v, 2);
        v += __shfl_xor(v, 4);
        v += __shfl_xor(v, 8);
        pr[rt][e] = v;
      }
    if (l15 == 0) {
#pragma unroll
      for (int rt = 0; rt < 4; ++rt)
#pragma unroll
        for (int e = 0; e < 4; ++e)
          red[rt * 16 + lq * 4 + e][wave] = pr[rt][e];
    }
    __syncthreads();

    // ---- LIF2 on wave 0: one thread per batch row ----
    if (tid < 64) {
      float c2 = bias2;
#pragma unroll
      for (int w = 0; w < 8; ++w) c2 += red[tid][w];
      float m   = fmaf(mem2, 0.9f, c2);
      float spk = fast_sigmoid(fmaf(m, 10.f, -10.f));
      mem2   = m - spk;
      spksum += spk;
    }
    __syncthreads();
  }

  if (tid < 64) {
    float y = fast_sigmoid(spksum * 0.1f);
    out[b0 + tid] = y;                      // FLOAT32 output
  }
}

extern "C" void kernel_launch(void* const* d_in, const int* in_sizes, int n_in,
                              void* d_out, int out_size, void* d_ws, size_t ws_size,
                              hipStream_t stream) {
  const float* x  = (const float*)d_in[0];
  const float* W1 = (const float*)d_in[1];
  const float* b1 = (const float*)d_in[2];
  const float* W2 = (const float*)d_in[3];
  const float* b2 = (const float*)d_in[4];
  float* out = (float*)d_out;
  (void)in_sizes; (void)n_in;

  const int grid = out_size / 64;   // out_size == B == 32768 -> 512 blocks

  if (ws_size >= 512 * 256 * sizeof(unsigned short)) {
    unsigned short* w1bf = (unsigned short*)d_ws;   // 256 KB
    w1_to_bf16<<<128, 256, 0, stream>>>(W1, w1bf);
    snn_main<true><<<grid, 512, 0, stream>>>(x, w1bf, W1, b1, W2, b2, out);
  } else {
    snn_main<false><<<grid, 512, 0, stream>>>(x, nullptr, W1, b1, W2, b2, out);
  }
}

// Round 6
// 296.975 us; speedup vs baseline: 1.2865x; 1.1566x over previous
//
#include <hip/hip_runtime.h>
#include <hip/hip_bf16.h>

// FraudSNN fused kernel: GEMM (bf16 MFMA) + LIF recurrence, T=10, F=256, H=512.
// R6: compiler pins VGPR=128 regardless of launch-bounds/waves_per_eu hints
// (tried (512,2),(512,1),waves_per_eu(2,2) -> always 128, ~90 MB spill writes).
// Restructure to FIT 128: 1024 threads (16 waves), wave owns 64 rows x 32 h-cols.
// mem1 32 regs + acc 32 + frags 24 + misc ~= 110 live < 128 -> no spills.

typedef short short8 __attribute__((ext_vector_type(8)));
typedef float f32x4 __attribute__((ext_vector_type(4)));

__device__ __forceinline__ unsigned short bfbits(float f) {
  union { __hip_bfloat16 h; unsigned short u; } c;
  c.h = __float2bfloat16(f);   // hardware RNE
  return c.u;
}

__device__ __forceinline__ unsigned int bfpack(float a, float b) {
  return (unsigned int)bfbits(a) | ((unsigned int)bfbits(b) << 16);
}

__device__ __forceinline__ float fast_sigmoid(float z) {
  float e = __expf(-z);
  return __builtin_amdgcn_rcpf(1.0f + e);
}

__global__ void w1_to_bf16(const float* __restrict__ w1, unsigned short* __restrict__ o) {
  int i = blockIdx.x * 256 + threadIdx.x;      // 32768 float4s = 131072 floats
  float4 v = reinterpret_cast<const float4*>(w1)[i];
  reinterpret_cast<uint2*>(o)[i] = make_uint2(bfpack(v.x, v.y), bfpack(v.z, v.w));
}

// 1024 threads = 16 waves. Block handles 64 batch rows; wave w owns 64 rows x h in [w*32, w*32+32).
template <bool USE_WS>
__global__
__attribute__((amdgpu_flat_work_group_size(1024, 1024)))
void snn_main(const float* __restrict__ x,
              const unsigned short* __restrict__ w1bf,  // bf16 W1 (if USE_WS)
              const float* __restrict__ w1f,            // fp32 W1 (fallback)
              const float* __restrict__ b1,
              const float* __restrict__ w2,
              const float* __restrict__ b2,
              float* __restrict__ out)
{
  __shared__ __align__(16) unsigned short xt[64][264];  // bf16 bits, +8 pad (33.8 KB)
  __shared__ float red[64][17];                         // [row][wave] partial cur2 (4.3 KB)

  const int tid  = threadIdx.x;
  const int lane = tid & 63;
  const int wave = tid >> 6;          // 0..15
  const int l15  = lane & 15;
  const int lq   = lane >> 4;         // 0..3
  const long b0  = (long)blockIdx.x * 64;
  const int h0   = wave * 32;         // 32 h-cols per wave (2 column-tiles of 16)

  float w2l[2], b1l[2];
#pragma unroll
  for (int ct = 0; ct < 2; ++ct) {
    int h = h0 + ct * 16 + l15;
    w2l[ct] = w2[h];
    b1l[ct] = b1[h];
  }
  const float bias2 = b2[0];

  float mem1[4][2][4];   // [rt][ct][e] : 32 regs
#pragma unroll
  for (int rt = 0; rt < 4; ++rt)
#pragma unroll
    for (int ct = 0; ct < 2; ++ct)
#pragma unroll
      for (int e = 0; e < 4; ++e) mem1[rt][ct][e] = 0.f;

  float mem2 = 0.f, spksum = 0.f;   // meaningful on tid<64 only

#pragma unroll 1
  for (int t = 0; t < 10; ++t) {
    // ---- stage x[b0..b0+63, t, :] -> LDS bf16 (4096 float4s over 1024 threads) ----
#pragma unroll
    for (int j = 0; j < 4; ++j) {
      int i  = tid + j * 1024;
      int r  = i >> 6;
      int c4 = i & 63;
      const float4 v = *reinterpret_cast<const float4*>(x + ((b0 + r) * 10 + t) * 256 + c4 * 4);
      *reinterpret_cast<uint2*>(&xt[r][c4 * 4]) =
          make_uint2(bfpack(v.x, v.y), bfpack(v.z, v.w));
    }
    __syncthreads();

    // ---- GEMM: cur1 = x @ W1^T + b1 (acc init = b1) ----
    f32x4 acc[4][2];   // 32 regs
#pragma unroll
    for (int rt = 0; rt < 4; ++rt)
#pragma unroll
      for (int ct = 0; ct < 2; ++ct) {
        f32x4 c = { b1l[ct], b1l[ct], b1l[ct], b1l[ct] };
        acc[rt][ct] = c;
      }

#pragma unroll
    for (int kk = 0; kk < 8; ++kk) {
      short8 a[4], bfr[2];
#pragma unroll
      for (int rt = 0; rt < 4; ++rt)
        a[rt] = *reinterpret_cast<const short8*>(&xt[rt * 16 + l15][kk * 32 + lq * 8]);
#pragma unroll
      for (int ct = 0; ct < 2; ++ct) {
        if constexpr (USE_WS) {
          bfr[ct] = *reinterpret_cast<const short8*>(
              w1bf + (h0 + ct * 16 + l15) * 256 + kk * 32 + lq * 8);
        } else {
          const float* wp = w1f + (h0 + ct * 16 + l15) * 256 + kk * 32 + lq * 8;
          const float4 v0 = *reinterpret_cast<const float4*>(wp);
          const float4 v1 = *reinterpret_cast<const float4*>(wp + 4);
          union { unsigned int u[4]; short8 s; } cv;
          cv.u[0] = bfpack(v0.x, v0.y);
          cv.u[1] = bfpack(v0.z, v0.w);
          cv.u[2] = bfpack(v1.x, v1.y);
          cv.u[3] = bfpack(v1.z, v1.w);
          bfr[ct] = cv.s;
        }
      }
#pragma unroll
      for (int rt = 0; rt < 4; ++rt)
#pragma unroll
        for (int ct = 0; ct < 2; ++ct)
          acc[rt][ct] = __builtin_amdgcn_mfma_f32_16x16x32_bf16(a[rt], bfr[ct], acc[rt][ct], 0, 0, 0);
    }

    // ---- LIF1 + partial W2 dot; reduce + stash per rt to keep pressure low ----
#pragma unroll
    for (int rt = 0; rt < 4; ++rt) {
      float pr[4] = {0.f, 0.f, 0.f, 0.f};
#pragma unroll
      for (int ct = 0; ct < 2; ++ct)
#pragma unroll
        for (int e = 0; e < 4; ++e) {
          float m   = fmaf(mem1[rt][ct][e], 0.9f, acc[rt][ct][e]);  // beta*mem + cur1
          float spk = fast_sigmoid(fmaf(m, 10.f, -10.f));           // sigmoid(10*(m-1))
          mem1[rt][ct][e] = m - spk;
          pr[e] = fmaf(spk, w2l[ct], pr[e]);
        }
      // reduce across the 16 lanes (h axis) sharing each row
#pragma unroll
      for (int e = 0; e < 4; ++e) {
        float v = pr[e];
        v += __shfl_xor(v, 1);
        v += __shfl_xor(v, 2);
        v += __shfl_xor(v, 4);
        v += __shfl_xor(v, 8);
        if (l15 == 0) red[rt * 16 + lq * 4 + e][wave] = v;
      }
    }
    __syncthreads();

    // ---- LIF2 on wave 0: one thread per batch row ----
    if (tid < 64) {
      float c2 = bias2;
#pragma unroll
      for (int w = 0; w < 16; ++w) c2 += red[tid][w];
      float m   = fmaf(mem2, 0.9f, c2);
      float spk = fast_sigmoid(fmaf(m, 10.f, -10.f));
      mem2   = m - spk;
      spksum += spk;
    }
    __syncthreads();
  }

  if (tid < 64) {
    float y = fast_sigmoid(spksum * 0.1f);
    out[b0 + tid] = y;                      // FLOAT32 output
  }
}

extern "C" void kernel_launch(void* const* d_in, const int* in_sizes, int n_in,
                              void* d_out, int out_size, void* d_ws, size_t ws_size,
                              hipStream_t stream) {
  const float* x  = (const float*)d_in[0];
  const float* W1 = (const float*)d_in[1];
  const float* b1 = (const float*)d_in[2];
  const float* W2 = (const float*)d_in[3];
  const float* b2 = (const float*)d_in[4];
  float* out = (float*)d_out;
  (void)in_sizes; (void)n_in;

  const int grid = out_size / 64;   // out_size == B == 32768 -> 512 blocks

  if (ws_size >= 512 * 256 * sizeof(unsigned short)) {
    unsigned short* w1bf = (unsigned short*)d_ws;   // 256 KB
    w1_to_bf16<<<128, 256, 0, stream>>>(W1, w1bf);
    snn_main<true><<<grid, 1024, 0, stream>>>(x, w1bf, W1, b1, W2, b2, out);
  } else {
    snn_main<false><<<grid, 1024, 0, stream>>>(x, nullptr, W1, b1, W2, b2, out);
  }
}

// Round 7
// 285.261 us; speedup vs baseline: 1.3394x; 1.0411x over previous
//
#include <hip/hip_runtime.h>
#include <hip/hip_bf16.h>

// FraudSNN fused kernel: GEMM (bf16 MFMA) + LIF recurrence, T=10, F=256, H=512.
// R7: the allocator budgets VGPRs from the occupancy cap (1024thr -> 2 blk/CU -> 64 VGPR)
// and spills the persistent mem1 state to HBM scratch (~106 MB writes). Fix structurally:
// mem1 lives in LDS (conflict-free per-thread slots). LDS=149KB also caps occupancy at
// 1 blk/CU -> 4 waves/EU -> compiler budgets 128 VGPRs; remaining live ~85 regs, no spill.

typedef short short8 __attribute__((ext_vector_type(8)));
typedef float f32x4 __attribute__((ext_vector_type(4)));

__device__ __forceinline__ unsigned short bfbits(float f) {
  union { __hip_bfloat16 h; unsigned short u; } c;
  c.h = __float2bfloat16(f);   // hardware RNE
  return c.u;
}

__device__ __forceinline__ unsigned int bfpack(float a, float b) {
  return (unsigned int)bfbits(a) | ((unsigned int)bfbits(b) << 16);
}

__device__ __forceinline__ float fast_sigmoid(float z) {
  float e = __expf(-z);
  return __builtin_amdgcn_rcpf(1.0f + e);
}

__global__ void w1_to_bf16(const float* __restrict__ w1, unsigned short* __restrict__ o) {
  int i = blockIdx.x * 256 + threadIdx.x;      // 32768 float4s = 131072 floats
  float4 v = reinterpret_cast<const float4*>(w1)[i];
  reinterpret_cast<uint2*>(o)[i] = make_uint2(bfpack(v.x, v.y), bfpack(v.z, v.w));
}

// 1024 threads = 16 waves. Block handles 64 batch rows; wave w owns 64 rows x h in [w*32, w*32+32).
template <bool USE_WS>
__global__
__attribute__((amdgpu_flat_work_group_size(1024, 1024), amdgpu_waves_per_eu(4, 4)))
void snn_main(const float* __restrict__ x,
              const unsigned short* __restrict__ w1bf,  // bf16 W1 (if USE_WS)
              const float* __restrict__ w1f,            // fp32 W1 (fallback)
              const float* __restrict__ b1,
              const float* __restrict__ w2,
              const float* __restrict__ b2,
              float* __restrict__ out)
{
  // mem1 state: plane p = rt*2+ct, per-thread f32x4 slot -> 8*1024*16 B = 128 KB
  __shared__ __align__(16) float mem_lds[8][1024][4];
  __shared__ __align__(16) unsigned short xt[64][132];  // one 128-wide k-half, bf16 (16.5 KB)
  __shared__ float red[64][17];                         // [row][wave] partial cur2 (4.3 KB)

  const int tid  = threadIdx.x;
  const int lane = tid & 63;
  const int wave = tid >> 6;          // 0..15
  const int l15  = lane & 15;
  const int lq   = lane >> 4;         // 0..3
  const long b0  = (long)blockIdx.x * 64;
  const int h0   = wave * 32;         // 32 h-cols per wave (2 col-tiles of 16)

  float w2l[2], b1l[2];
#pragma unroll
  for (int ct = 0; ct < 2; ++ct) {
    int h = h0 + ct * 16 + l15;
    w2l[ct] = w2[h];
    b1l[ct] = b1[h];
  }
  const float bias2 = b2[0];

  // zero-init mem1 planes (own slot each; first __syncthreads below fences it)
#pragma unroll
  for (int p = 0; p < 8; ++p) {
    f32x4 z = {0.f, 0.f, 0.f, 0.f};
    *reinterpret_cast<f32x4*>(&mem_lds[p][tid][0]) = z;
  }

  float mem2 = 0.f, spksum = 0.f;   // meaningful on tid<64 only

#pragma unroll 1
  for (int t = 0; t < 10; ++t) {
    f32x4 acc[4][2];   // 32 regs
#pragma unroll
    for (int rt = 0; rt < 4; ++rt)
#pragma unroll
      for (int ct = 0; ct < 2; ++ct) {
        f32x4 c = { b1l[ct], b1l[ct], b1l[ct], b1l[ct] };
        acc[rt][ct] = c;
      }

    // ---- two k-halves: stage 128 k-cols then 4 kk-steps of MFMA ----
#pragma unroll 1
    for (int half = 0; half < 2; ++half) {
      // stage x[b0..b0+63, t, half*128 .. +128) -> xt (2048 float4s over 1024 threads)
#pragma unroll
      for (int j = 0; j < 2; ++j) {
        int i  = tid + j * 1024;
        int r  = i >> 5;            // 32 float4 per row-half
        int c4 = i & 31;
        const float4 v = *reinterpret_cast<const float4*>(
            x + ((b0 + r) * 10 + t) * 256 + half * 128 + c4 * 4);
        *reinterpret_cast<uint2*>(&xt[r][c4 * 4]) =
            make_uint2(bfpack(v.x, v.y), bfpack(v.z, v.w));
      }
      __syncthreads();

#pragma unroll
      for (int kkL = 0; kkL < 4; ++kkL) {
        const int kkg = half * 4 + kkL;
        short8 a[4], bfr[2];
#pragma unroll
        for (int rt = 0; rt < 4; ++rt)
          a[rt] = *reinterpret_cast<const short8*>(&xt[rt * 16 + l15][kkL * 32 + lq * 8]);
#pragma unroll
        for (int ct = 0; ct < 2; ++ct) {
          if constexpr (USE_WS) {
            bfr[ct] = *reinterpret_cast<const short8*>(
                w1bf + (h0 + ct * 16 + l15) * 256 + kkg * 32 + lq * 8);
          } else {
            const float* wp = w1f + (h0 + ct * 16 + l15) * 256 + kkg * 32 + lq * 8;
            const float4 v0 = *reinterpret_cast<const float4*>(wp);
            const float4 v1 = *reinterpret_cast<const float4*>(wp + 4);
            union { unsigned int u[4]; short8 s; } cv;
            cv.u[0] = bfpack(v0.x, v0.y);
            cv.u[1] = bfpack(v0.z, v0.w);
            cv.u[2] = bfpack(v1.x, v1.y);
            cv.u[3] = bfpack(v1.z, v1.w);
            bfr[ct] = cv.s;
          }
        }
#pragma unroll
        for (int rt = 0; rt < 4; ++rt)
#pragma unroll
          for (int ct = 0; ct < 2; ++ct)
            acc[rt][ct] = __builtin_amdgcn_mfma_f32_16x16x32_bf16(a[rt], bfr[ct], acc[rt][ct], 0, 0, 0);
      }
      if (half == 0) __syncthreads();   // xt reads done before half-1 staging overwrites
    }

    // ---- LIF1 (mem1 in LDS, own slot) + partial W2 dot; reduce per rt ----
#pragma unroll
    for (int rt = 0; rt < 4; ++rt) {
      float pr[4] = {0.f, 0.f, 0.f, 0.f};
#pragma unroll
      for (int ct = 0; ct < 2; ++ct) {
        f32x4* slot = reinterpret_cast<f32x4*>(&mem_lds[rt * 2 + ct][tid][0]);
        f32x4 mv = *slot;
#pragma unroll
        for (int e = 0; e < 4; ++e) {
          float m   = fmaf(mv[e], 0.9f, acc[rt][ct][e]);   // beta*mem + cur1
          float spk = fast_sigmoid(fmaf(m, 10.f, -10.f));  // sigmoid(10*(m-1))
          mv[e] = m - spk;
          pr[e] = fmaf(spk, w2l[ct], pr[e]);
        }
        *slot = mv;
      }
      // reduce across the 16 lanes (h axis) sharing each row
#pragma unroll
      for (int e = 0; e < 4; ++e) {
        float v = pr[e];
        v += __shfl_xor(v, 1);
        v += __shfl_xor(v, 2);
        v += __shfl_xor(v, 4);
        v += __shfl_xor(v, 8);
        if (l15 == 0) red[rt * 16 + lq * 4 + e][wave] = v;
      }
    }
    __syncthreads();

    // ---- LIF2 on wave 0: one thread per batch row ----
    if (tid < 64) {
      float c2 = bias2;
#pragma unroll
      for (int w = 0; w < 16; ++w) c2 += red[tid][w];
      float m   = fmaf(mem2, 0.9f, c2);
      float spk = fast_sigmoid(fmaf(m, 10.f, -10.f));
      mem2   = m - spk;
      spksum += spk;
    }
    __syncthreads();   // protects red + xt for next t
  }

  if (tid < 64) {
    float y = fast_sigmoid(spksum * 0.1f);
    out[b0 + tid] = y;                      // FLOAT32 output
  }
}

extern "C" void kernel_launch(void* const* d_in, const int* in_sizes, int n_in,
                              void* d_out, int out_size, void* d_ws, size_t ws_size,
                              hipStream_t stream) {
  const float* x  = (const float*)d_in[0];
  const float* W1 = (const float*)d_in[1];
  const float* b1 = (const float*)d_in[2];
  const float* W2 = (const float*)d_in[3];
  const float* b2 = (const float*)d_in[4];
  float* out = (float*)d_out;
  (void)in_sizes; (void)n_in;

  const int grid = out_size / 64;   // out_size == B == 32768 -> 512 blocks

  if (ws_size >= 512 * 256 * sizeof(unsigned short)) {
    unsigned short* w1bf = (unsigned short*)d_ws;   // 256 KB
    w1_to_bf16<<<128, 256, 0, stream>>>(W1, w1bf);
    snn_main<true><<<grid, 1024, 0, stream>>>(x, w1bf, W1, b1, W2, b2, out);
  } else {
    snn_main<false><<<grid, 1024, 0, stream>>>(x, nullptr, W1, b1, W2, b2, out);
  }
}

// Round 8
// 256.630 us; speedup vs baseline: 1.4888x; 1.1116x over previous
//
#include <hip/hip_runtime.h>
#include <hip/hip_bf16.h>

// FraudSNN fused kernel: GEMM (bf16 MFMA) + LIF recurrence, T=10, F=256, H=512.
// R8: R7 killed spills (WRITE 106MB->0.13MB) but is latency-bound (538 GB/s, MfmaUtil 11%,
// 1 block/CU, 5 barriers/t, staging + W1-L2 latency fully exposed). This round:
//  - T14 prefetch: x half-tiles loaded to regs one phase ahead (latency hides under compute)
//  - W1 kk0..3 fragments persistent in registers (32 VGPR) -> half-0 MFMA phase is pure LDS+MFMA
//  - LIF2 computed redundantly by all threads (kills 64-thread serial phase + 1 barrier)
// mem1 stays in LDS (conflict-free per-thread f32x4 slots; proven 0-conflict, 0-spill).

typedef short short8 __attribute__((ext_vector_type(8)));
typedef float f32x4 __attribute__((ext_vector_type(4)));

__device__ __forceinline__ unsigned short bfbits(float f) {
  union { __hip_bfloat16 h; unsigned short u; } c;
  c.h = __float2bfloat16(f);   // hardware RNE
  return c.u;
}

__device__ __forceinline__ unsigned int bfpack(float a, float b) {
  return (unsigned int)bfbits(a) | ((unsigned int)bfbits(b) << 16);
}

__device__ __forceinline__ float fast_sigmoid(float z) {
  float e = __expf(-z);
  return __builtin_amdgcn_rcpf(1.0f + e);
}

__global__ void w1_to_bf16(const float* __restrict__ w1, unsigned short* __restrict__ o) {
  int i = blockIdx.x * 256 + threadIdx.x;      // 32768 float4s = 131072 floats
  float4 v = reinterpret_cast<const float4*>(w1)[i];
  reinterpret_cast<uint2*>(o)[i] = make_uint2(bfpack(v.x, v.y), bfpack(v.z, v.w));
}

// 1024 threads = 16 waves. Block: 64 batch rows; wave w owns 64 rows x h in [w*32, w*32+32).
template <bool USE_WS>
__global__
__attribute__((amdgpu_flat_work_group_size(1024, 1024)))
void snn_main(const float* __restrict__ x,
              const unsigned short* __restrict__ w1bf,  // bf16 W1 (if USE_WS)
              const float* __restrict__ w1f,            // fp32 W1 (fallback)
              const float* __restrict__ b1,
              const float* __restrict__ w2,
              const float* __restrict__ b2,
              float* __restrict__ out)
{
  // mem1 state: plane p = rt*2+ct, per-thread f32x4 slot -> 8*1024*16 B = 128 KB
  __shared__ __align__(16) float mem_lds[8][1024][4];
  __shared__ __align__(16) unsigned short xt[64][132];  // one 128-col k-half, bf16 (16.9 KB)
  __shared__ float red[64][17];                         // [row][wave] partial cur2 (4.3 KB)

  const int tid  = threadIdx.x;
  const int lane = tid & 63;
  const int wave = tid >> 6;          // 0..15
  const int l15  = lane & 15;
  const int lq   = lane >> 4;         // 0..3
  const long b0  = (long)blockIdx.x * 64;
  const int h0   = wave * 32;         // 32 h-cols per wave (2 col-tiles of 16)

  float w2l[2], b1l[2];
#pragma unroll
  for (int ct = 0; ct < 2; ++ct) {
    int h = h0 + ct * 16 + l15;
    w2l[ct] = w2[h];
    b1l[ct] = b1[h];
  }
  const float bias2 = b2[0];

  // ---- persistent W1 fragments for k-half 0 (kk = 0..3): 2ct x 4kk x 16B = 32 VGPR ----
  short8 w1r[2][4];
#pragma unroll
  for (int ct = 0; ct < 2; ++ct)
#pragma unroll
    for (int kk = 0; kk < 4; ++kk) {
      if constexpr (USE_WS) {
        w1r[ct][kk] = *reinterpret_cast<const short8*>(
            w1bf + (h0 + ct * 16 + l15) * 256 + kk * 32 + lq * 8);
      } else {
        const float* wp = w1f + (h0 + ct * 16 + l15) * 256 + kk * 32 + lq * 8;
        const float4 v0 = *reinterpret_cast<const float4*>(wp);
        const float4 v1 = *reinterpret_cast<const float4*>(wp + 4);
        union { unsigned int u[4]; short8 s; } cv;
        cv.u[0] = bfpack(v0.x, v0.y);
        cv.u[1] = bfpack(v0.z, v0.w);
        cv.u[2] = bfpack(v1.x, v1.y);
        cv.u[3] = bfpack(v1.z, v1.w);
        w1r[ct][kk] = cv.s;
      }
    }

  // zero-init mem1 planes (own slot each; consumed by same thread only)
#pragma unroll
  for (int p = 0; p < 8; ++p) {
    f32x4 z = {0.f, 0.f, 0.f, 0.f};
    *reinterpret_cast<f32x4*>(&mem_lds[p][tid][0]) = z;
  }

  float mem2 = 0.f, spksum = 0.f;   // per-thread redundant (16 replicas per row)

  // staging geometry: thread stages rows r0 and r0+32, float4 index c4 within a 128-col half
  const int r0 = tid >> 5;
  const int c4 = tid & 31;
  const float* xp0 = x + (b0 + r0) * 2560 + c4 * 4;        // row r0, t=0, k=0
  const float* xp1 = x + (b0 + r0 + 32) * 2560 + c4 * 4;   // row r0+32

  // prologue: prefetch half0 of t=0
  float4 pf0 = *reinterpret_cast<const float4*>(xp0);
  float4 pf1 = *reinterpret_cast<const float4*>(xp1);

#pragma unroll 1
  for (int t = 0; t < 10; ++t) {
    // ---- A: write prefetched half0 -> xt; issue half1 loads (hide under MFMA-half0) ----
    *reinterpret_cast<uint2*>(&xt[r0][c4 * 4]) =
        make_uint2(bfpack(pf0.x, pf0.y), bfpack(pf0.z, pf0.w));
    *reinterpret_cast<uint2*>(&xt[r0 + 32][c4 * 4]) =
        make_uint2(bfpack(pf1.x, pf1.y), bfpack(pf1.z, pf1.w));
    pf0 = *reinterpret_cast<const float4*>(xp0 + t * 256 + 128);
    pf1 = *reinterpret_cast<const float4*>(xp1 + t * 256 + 128);
    __syncthreads();

    f32x4 acc[4][2];
#pragma unroll
    for (int rt = 0; rt < 4; ++rt)
#pragma unroll
      for (int ct = 0; ct < 2; ++ct) {
        f32x4 c = { b1l[ct], b1l[ct], b1l[ct], b1l[ct] };
        acc[rt][ct] = c;
      }

    // ---- B: MFMA k-half 0 — W1 from registers, pure LDS+MFMA ----
#pragma unroll
    for (int kkL = 0; kkL < 4; ++kkL) {
      short8 a[4];
#pragma unroll
      for (int rt = 0; rt < 4; ++rt)
        a[rt] = *reinterpret_cast<const short8*>(&xt[rt * 16 + l15][kkL * 32 + lq * 8]);
#pragma unroll
      for (int rt = 0; rt < 4; ++rt)
#pragma unroll
        for (int ct = 0; ct < 2; ++ct)
          acc[rt][ct] = __builtin_amdgcn_mfma_f32_16x16x32_bf16(a[rt], w1r[ct][kkL], acc[rt][ct], 0, 0, 0);
    }
    __syncthreads();

    // ---- D: write half1 -> xt; issue half0 loads of t+1 (hide under MFMA-half1 + LIF) ----
    *reinterpret_cast<uint2*>(&xt[r0][c4 * 4]) =
        make_uint2(bfpack(pf0.x, pf0.y), bfpack(pf0.z, pf0.w));
    *reinterpret_cast<uint2*>(&xt[r0 + 32][c4 * 4]) =
        make_uint2(bfpack(pf1.x, pf1.y), bfpack(pf1.z, pf1.w));
    const int tn = (t < 9) ? t + 1 : 9;   // t=9: harmless re-read, keeps code branch-free
    pf0 = *reinterpret_cast<const float4*>(xp0 + tn * 256);
    pf1 = *reinterpret_cast<const float4*>(xp1 + tn * 256);
    __syncthreads();

    // ---- E: MFMA k-half 1 — W1 from L2 (w1bf), loads pipelined across unrolled kkL ----
#pragma unroll
    for (int kkL = 0; kkL < 4; ++kkL) {
      const int kkg = 4 + kkL;
      short8 a[4], bfr[2];
#pragma unroll
      for (int rt = 0; rt < 4; ++rt)
        a[rt] = *reinterpret_cast<const short8*>(&xt[rt * 16 + l15][kkL * 32 + lq * 8]);
#pragma unroll
      for (int ct = 0; ct < 2; ++ct) {
        if constexpr (USE_WS) {
          bfr[ct] = *reinterpret_cast<const short8*>(
              w1bf + (h0 + ct * 16 + l15) * 256 + kkg * 32 + lq * 8);
        } else {
          const float* wp = w1f + (h0 + ct * 16 + l15) * 256 + kkg * 32 + lq * 8;
          const float4 v0 = *reinterpret_cast<const float4*>(wp);
          const float4 v1 = *reinterpret_cast<const float4*>(wp + 4);
          union { unsigned int u[4]; short8 s; } cv;
          cv.u[0] = bfpack(v0.x, v0.y);
          cv.u[1] = bfpack(v0.z, v0.w);
          cv.u[2] = bfpack(v1.x, v1.y);
          cv.u[3] = bfpack(v1.z, v1.w);
          bfr[ct] = cv.s;
        }
      }
#pragma unroll
      for (int rt = 0; rt < 4; ++rt)
#pragma unroll
        for (int ct = 0; ct < 2; ++ct)
          acc[rt][ct] = __builtin_amdgcn_mfma_f32_16x16x32_bf16(a[rt], bfr[ct], acc[rt][ct], 0, 0, 0);
    }

    // ---- F: LIF1 (mem1 in LDS) + partial W2 dot; reduce per rt ----
#pragma unroll
    for (int rt = 0; rt < 4; ++rt) {
      float pr[4] = {0.f, 0.f, 0.f, 0.f};
#pragma unroll
      for (int ct = 0; ct < 2; ++ct) {
        f32x4* slot = reinterpret_cast<f32x4*>(&mem_lds[rt * 2 + ct][tid][0]);
        f32x4 mv = *slot;
#pragma unroll
        for (int e = 0; e < 4; ++e) {
          float m   = fmaf(mv[e], 0.9f, acc[rt][ct][e]);   // beta*mem + cur1
          float spk = fast_sigmoid(fmaf(m, 10.f, -10.f));  // sigmoid(10*(m-1))
          mv[e] = m - spk;
          pr[e] = fmaf(spk, w2l[ct], pr[e]);
        }
        *slot = mv;
      }
#pragma unroll
      for (int e = 0; e < 4; ++e) {
        float v = pr[e];
        v += __shfl_xor(v, 1);
        v += __shfl_xor(v, 2);
        v += __shfl_xor(v, 4);
        v += __shfl_xor(v, 8);
        if (l15 == 0) red[rt * 16 + lq * 4 + e][wave] = v;
      }
    }
    __syncthreads();

    // ---- H: LIF2, redundant on all threads (row = lane); no trailing barrier needed:
    //      red is next written in F(t+1), which is behind two barriers (A,C of t+1) ----
    {
      float c2 = bias2;
#pragma unroll
      for (int w = 0; w < 16; ++w) c2 += red[lane][w];
      float m   = fmaf(mem2, 0.9f, c2);
      float spk = fast_sigmoid(fmaf(m, 10.f, -10.f));
      mem2   = m - spk;
      spksum += spk;
    }
  }

  if (tid < 64) {
    float y = fast_sigmoid(spksum * 0.1f);
    out[b0 + tid] = y;                      // FLOAT32 output
  }
}

extern "C" void kernel_launch(void* const* d_in, const int* in_sizes, int n_in,
                              void* d_out, int out_size, void* d_ws, size_t ws_size,
                              hipStream_t stream) {
  const float* x  = (const float*)d_in[0];
  const float* W1 = (const float*)d_in[1];
  const float* b1 = (const float*)d_in[2];
  const float* W2 = (const float*)d_in[3];
  const float* b2 = (const float*)d_in[4];
  float* out = (float*)d_out;
  (void)in_sizes; (void)n_in;

  const int grid = out_size / 64;   // out_size == B == 32768 -> 512 blocks

  if (ws_size >= 512 * 256 * sizeof(unsigned short)) {
    unsigned short* w1bf = (unsigned short*)d_ws;   // 256 KB
    w1_to_bf16<<<128, 256, 0, stream>>>(W1, w1bf);
    snn_main<true><<<grid, 1024, 0, stream>>>(x, w1bf, W1, b1, W2, b2, out);
  } else {
    snn_main<false><<<grid, 1024, 0, stream>>>(x, nullptr, W1, b1, W2, b2, out);
  }
}

// Round 9
// 255.724 us; speedup vs baseline: 1.4941x; 1.0035x over previous
//
#include <hip/hip_runtime.h>
#include <hip/hip_bf16.h>

// FraudSNN fused kernel: GEMM (bf16 MFMA) + LIF recurrence, T=10, F=256, H=512.
// R9: R8 accidentally DROPPED amdgpu_waves_per_eu(4,4) -> compiler defaulted to a
// 64-VGPR budget (2 blk/CU heuristic, ignores our 149KB LDS) and re-spilled 66MB.
// Restore the attribute; keep R8 structure (T14 prefetch, W1-half in regs, redundant
// LIF2) unchanged. Live regs ~119 <= 128 budget at 4 waves/EU.

typedef short short8 __attribute__((ext_vector_type(8)));
typedef float f32x4 __attribute__((ext_vector_type(4)));

__device__ __forceinline__ unsigned short bfbits(float f) {
  union { __hip_bfloat16 h; unsigned short u; } c;
  c.h = __float2bfloat16(f);   // hardware RNE
  return c.u;
}

__device__ __forceinline__ unsigned int bfpack(float a, float b) {
  return (unsigned int)bfbits(a) | ((unsigned int)bfbits(b) << 16);
}

__device__ __forceinline__ float fast_sigmoid(float z) {
  float e = __expf(-z);
  return __builtin_amdgcn_rcpf(1.0f + e);
}

__global__ void w1_to_bf16(const float* __restrict__ w1, unsigned short* __restrict__ o) {
  int i = blockIdx.x * 256 + threadIdx.x;      // 32768 float4s = 131072 floats
  float4 v = reinterpret_cast<const float4*>(w1)[i];
  reinterpret_cast<uint2*>(o)[i] = make_uint2(bfpack(v.x, v.y), bfpack(v.z, v.w));
}

// 1024 threads = 16 waves. Block: 64 batch rows; wave w owns 64 rows x h in [w*32, w*32+32).
template <bool USE_WS>
__global__
__attribute__((amdgpu_flat_work_group_size(1024, 1024), amdgpu_waves_per_eu(4, 4)))
void snn_main(const float* __restrict__ x,
              const unsigned short* __restrict__ w1bf,  // bf16 W1 (if USE_WS)
              const float* __restrict__ w1f,            // fp32 W1 (fallback)
              const float* __restrict__ b1,
              const float* __restrict__ w2,
              const float* __restrict__ b2,
              float* __restrict__ out)
{
  // mem1 state: plane p = rt*2+ct, per-thread f32x4 slot -> 8*1024*16 B = 128 KB
  __shared__ __align__(16) float mem_lds[8][1024][4];
  __shared__ __align__(16) unsigned short xt[64][132];  // one 128-col k-half, bf16 (16.9 KB)
  __shared__ float red[64][17];                         // [row][wave] partial cur2 (4.3 KB)

  const int tid  = threadIdx.x;
  const int lane = tid & 63;
  const int wave = tid >> 6;          // 0..15
  const int l15  = lane & 15;
  const int lq   = lane >> 4;         // 0..3
  const long b0  = (long)blockIdx.x * 64;
  const int h0   = wave * 32;         // 32 h-cols per wave (2 col-tiles of 16)

  float w2l[2], b1l[2];
#pragma unroll
  for (int ct = 0; ct < 2; ++ct) {
    int h = h0 + ct * 16 + l15;
    w2l[ct] = w2[h];
    b1l[ct] = b1[h];
  }
  const float bias2 = b2[0];

  // ---- persistent W1 fragments for k-half 0 (kk = 0..3): 2ct x 4kk x 16B = 32 VGPR ----
  short8 w1r[2][4];
#pragma unroll
  for (int ct = 0; ct < 2; ++ct)
#pragma unroll
    for (int kk = 0; kk < 4; ++kk) {
      if constexpr (USE_WS) {
        w1r[ct][kk] = *reinterpret_cast<const short8*>(
            w1bf + (h0 + ct * 16 + l15) * 256 + kk * 32 + lq * 8);
      } else {
        const float* wp = w1f + (h0 + ct * 16 + l15) * 256 + kk * 32 + lq * 8;
        const float4 v0 = *reinterpret_cast<const float4*>(wp);
        const float4 v1 = *reinterpret_cast<const float4*>(wp + 4);
        union { unsigned int u[4]; short8 s; } cv;
        cv.u[0] = bfpack(v0.x, v0.y);
        cv.u[1] = bfpack(v0.z, v0.w);
        cv.u[2] = bfpack(v1.x, v1.y);
        cv.u[3] = bfpack(v1.z, v1.w);
        w1r[ct][kk] = cv.s;
      }
    }

  // zero-init mem1 planes (own slot each; consumed by same thread only)
#pragma unroll
  for (int p = 0; p < 8; ++p) {
    f32x4 z = {0.f, 0.f, 0.f, 0.f};
    *reinterpret_cast<f32x4*>(&mem_lds[p][tid][0]) = z;
  }

  float mem2 = 0.f, spksum = 0.f;   // per-thread redundant (16 replicas per row)

  // staging geometry: thread stages rows r0 and r0+32, float4 index c4 within a 128-col half
  const int r0 = tid >> 5;
  const int c4 = tid & 31;
  const float* xp0 = x + (b0 + r0) * 2560 + c4 * 4;        // row r0, t=0, k=0
  const float* xp1 = x + (b0 + r0 + 32) * 2560 + c4 * 4;   // row r0+32

  // prologue: prefetch half0 of t=0
  float4 pf0 = *reinterpret_cast<const float4*>(xp0);
  float4 pf1 = *reinterpret_cast<const float4*>(xp1);

#pragma unroll 1
  for (int t = 0; t < 10; ++t) {
    // ---- A: write prefetched half0 -> xt; issue half1 loads (hide under MFMA-half0) ----
    *reinterpret_cast<uint2*>(&xt[r0][c4 * 4]) =
        make_uint2(bfpack(pf0.x, pf0.y), bfpack(pf0.z, pf0.w));
    *reinterpret_cast<uint2*>(&xt[r0 + 32][c4 * 4]) =
        make_uint2(bfpack(pf1.x, pf1.y), bfpack(pf1.z, pf1.w));
    pf0 = *reinterpret_cast<const float4*>(xp0 + t * 256 + 128);
    pf1 = *reinterpret_cast<const float4*>(xp1 + t * 256 + 128);
    __syncthreads();

    f32x4 acc[4][2];
#pragma unroll
    for (int rt = 0; rt < 4; ++rt)
#pragma unroll
      for (int ct = 0; ct < 2; ++ct) {
        f32x4 c = { b1l[ct], b1l[ct], b1l[ct], b1l[ct] };
        acc[rt][ct] = c;
      }

    // ---- B: MFMA k-half 0 — W1 from registers, pure LDS+MFMA ----
#pragma unroll
    for (int kkL = 0; kkL < 4; ++kkL) {
      short8 a[4];
#pragma unroll
      for (int rt = 0; rt < 4; ++rt)
        a[rt] = *reinterpret_cast<const short8*>(&xt[rt * 16 + l15][kkL * 32 + lq * 8]);
#pragma unroll
      for (int rt = 0; rt < 4; ++rt)
#pragma unroll
        for (int ct = 0; ct < 2; ++ct)
          acc[rt][ct] = __builtin_amdgcn_mfma_f32_16x16x32_bf16(a[rt], w1r[ct][kkL], acc[rt][ct], 0, 0, 0);
    }
    __syncthreads();

    // ---- D: write half1 -> xt; issue half0 loads of t+1 (hide under MFMA-half1 + LIF) ----
    *reinterpret_cast<uint2*>(&xt[r0][c4 * 4]) =
        make_uint2(bfpack(pf0.x, pf0.y), bfpack(pf0.z, pf0.w));
    *reinterpret_cast<uint2*>(&xt[r0 + 32][c4 * 4]) =
        make_uint2(bfpack(pf1.x, pf1.y), bfpack(pf1.z, pf1.w));
    const int tn = (t < 9) ? t + 1 : 9;   // t=9: harmless re-read, keeps code branch-free
    pf0 = *reinterpret_cast<const float4*>(xp0 + tn * 256);
    pf1 = *reinterpret_cast<const float4*>(xp1 + tn * 256);
    __syncthreads();

    // ---- E: MFMA k-half 1 — W1 from L2 (w1bf), loads pipelined across unrolled kkL ----
#pragma unroll
    for (int kkL = 0; kkL < 4; ++kkL) {
      const int kkg = 4 + kkL;
      short8 a[4], bfr[2];
#pragma unroll
      for (int rt = 0; rt < 4; ++rt)
        a[rt] = *reinterpret_cast<const short8*>(&xt[rt * 16 + l15][kkL * 32 + lq * 8]);
#pragma unroll
      for (int ct = 0; ct < 2; ++ct) {
        if constexpr (USE_WS) {
          bfr[ct] = *reinterpret_cast<const short8*>(
              w1bf + (h0 + ct * 16 + l15) * 256 + kkg * 32 + lq * 8);
        } else {
          const float* wp = w1f + (h0 + ct * 16 + l15) * 256 + kkg * 32 + lq * 8;
          const float4 v0 = *reinterpret_cast<const float4*>(wp);
          const float4 v1 = *reinterpret_cast<const float4*>(wp + 4);
          union { unsigned int u[4]; short8 s; } cv;
          cv.u[0] = bfpack(v0.x, v0.y);
          cv.u[1] = bfpack(v0.z, v0.w);
          cv.u[2] = bfpack(v1.x, v1.y);
          cv.u[3] = bfpack(v1.z, v1.w);
          bfr[ct] = cv.s;
        }
      }
#pragma unroll
      for (int rt = 0; rt < 4; ++rt)
#pragma unroll
        for (int ct = 0; ct < 2; ++ct)
          acc[rt][ct] = __builtin_amdgcn_mfma_f32_16x16x32_bf16(a[rt], bfr[ct], acc[rt][ct], 0, 0, 0);
    }

    // ---- F: LIF1 (mem1 in LDS) + partial W2 dot; reduce per rt ----
#pragma unroll
    for (int rt = 0; rt < 4; ++rt) {
      float pr[4] = {0.f, 0.f, 0.f, 0.f};
#pragma unroll
      for (int ct = 0; ct < 2; ++ct) {
        f32x4* slot = reinterpret_cast<f32x4*>(&mem_lds[rt * 2 + ct][tid][0]);
        f32x4 mv = *slot;
#pragma unroll
        for (int e = 0; e < 4; ++e) {
          float m   = fmaf(mv[e], 0.9f, acc[rt][ct][e]);   // beta*mem + cur1
          float spk = fast_sigmoid(fmaf(m, 10.f, -10.f));  // sigmoid(10*(m-1))
          mv[e] = m - spk;
          pr[e] = fmaf(spk, w2l[ct], pr[e]);
        }
        *slot = mv;
      }
#pragma unroll
      for (int e = 0; e < 4; ++e) {
        float v = pr[e];
        v += __shfl_xor(v, 1);
        v += __shfl_xor(v, 2);
        v += __shfl_xor(v, 4);
        v += __shfl_xor(v, 8);
        if (l15 == 0) red[rt * 16 + lq * 4 + e][wave] = v;
      }
    }
    __syncthreads();

    // ---- H: LIF2, redundant on all threads (row = lane); red next written in F(t+1),
    //      which is behind the A and D barriers of t+1 ----
    {
      float c2 = bias2;
#pragma unroll
      for (int w = 0; w < 16; ++w) c2 += red[lane][w];
      float m   = fmaf(mem2, 0.9f, c2);
      float spk = fast_sigmoid(fmaf(m, 10.f, -10.f));
      mem2   = m - spk;
      spksum += spk;
    }
  }

  if (tid < 64) {
    float y = fast_sigmoid(spksum * 0.1f);
    out[b0 + tid] = y;                      // FLOAT32 output
  }
}

extern "C" void kernel_launch(void* const* d_in, const int* in_sizes, int n_in,
                              void* d_out, int out_size, void* d_ws, size_t ws_size,
                              hipStream_t stream) {
  const float* x  = (const float*)d_in[0];
  const float* W1 = (const float*)d_in[1];
  const float* b1 = (const float*)d_in[2];
  const float* W2 = (const float*)d_in[3];
  const float* b2 = (const float*)d_in[4];
  float* out = (float*)d_out;
  (void)in_sizes; (void)n_in;

  const int grid = out_size / 64;   // out_size == B == 32768 -> 512 blocks

  if (ws_size >= 512 * 256 * sizeof(unsigned short)) {
    unsigned short* w1bf = (unsigned short*)d_ws;   // 256 KB
    w1_to_bf16<<<128, 256, 0, stream>>>(W1, w1bf);
    snn_main<true><<<grid, 1024, 0, stream>>>(x, w1bf, W1, b1, W2, b2, out);
  } else {
    snn_main<false><<<grid, 1024, 0, stream>>>(x, nullptr, W1, b1, W2, b2, out);
  }
}